// Round 2
// baseline (1205.631 us; speedup 1.0000x reference)
//
#include <hip/hip_runtime.h>

#define TWO_PI 6.283185307179586f

// ---------------- wavelet decompose: x[b,2n,2n,64,9] -> d,s [b,n,n,64,9] ----------------
__global__ void wavelet_kernel(const float* __restrict__ x,
                               float* __restrict__ d, float* __restrict__ s,
                               const float* __restrict__ ec_d,
                               const float* __restrict__ ec_s,
                               int n, int total)
{
    __shared__ float wd[324], wsm[324];
    for (int i = threadIdx.x; i < 324; i += blockDim.x) { wd[i] = ec_d[i]; wsm[i] = ec_s[i]; }
    __syncthreads();
    int idx = blockIdx.x * blockDim.x + threadIdx.x;
    if (idx >= total) return;
    int it = idx & 63; int tmp = idx >> 6;
    int iy = tmp % n; tmp /= n;
    int ix = tmp % n; int b = tmp / n;
    int n2 = 2 * n;
    const float* base = x + ((((size_t)(b * n2 + 2 * ix) * n2 + 2 * iy) * 64 + it) * 9);
    const float* p0 = base;
    const float* p1 = base + 64 * 9;               // (2ix, 2iy+1)
    const float* p2 = base + (size_t)n2 * 64 * 9;  // (2ix+1, 2iy)
    const float* p3 = p2 + 64 * 9;                 // (2ix+1, 2iy+1)
    float a[36];
    #pragma unroll
    for (int k = 0; k < 9; ++k) { a[k] = p0[k]; a[9+k] = p1[k]; a[18+k] = p2[k]; a[27+k] = p3[k]; }
    size_t ob = (size_t)idx * 9;
    #pragma unroll
    for (int oc = 0; oc < 9; ++oc) {
        float vd = 0.f, vs = 0.f;
        #pragma unroll
        for (int k = 0; k < 36; ++k) { vd += a[k] * wd[k*9+oc]; vs += a[k] * wsm[k*9+oc]; }
        d[ob+oc] = vd; s[ob+oc] = vs;
    }
}

// ------------- dual conv3d(3,SAME) + bias + ReLU + Linear, T-blocked by 4 -------------
// blockIdx.y == 0: B-conv: in_s -> accumulate into Ud
// blockIdx.y == 1: C-conv: in_d -> write Us
__global__ void conv2_kernel(const float* __restrict__ in_s, float* __restrict__ ud,
                             const float* __restrict__ in_d, float* __restrict__ us,
                             const float* __restrict__ Bcw, const float* __restrict__ Bcb,
                             const float* __restrict__ Blw, const float* __restrict__ Blb,
                             const float* __restrict__ Ccw, const float* __restrict__ Ccb,
                             const float* __restrict__ Clw, const float* __restrict__ Clb,
                             int n, int total4)
{
    const int which = blockIdx.y;
    const float* cw = which ? Ccw : Bcw;
    const float* cb = which ? Ccb : Bcb;
    const float* lw = which ? Clw : Blw;
    const float* lb = which ? Clb : Blb;
    const float* in = which ? in_d : in_s;
    float* out      = which ? us   : ud;

    __shared__ float scw[2187], slw[81], scb[9], slb[9];
    for (int i = threadIdx.x; i < 2187; i += blockDim.x) scw[i] = cw[i];
    if (threadIdx.x < 81) slw[threadIdx.x] = lw[threadIdx.x];
    if (threadIdx.x < 9) { scb[threadIdx.x] = cb[threadIdx.x]; slb[threadIdx.x] = lb[threadIdx.x]; }
    __syncthreads();
    int idx = blockIdx.x * blockDim.x + threadIdx.x;
    if (idx >= total4) return;
    int itb = idx & 15; int tmp = idx >> 4;
    int iy = tmp % n; int t2 = tmp / n;
    int ix = t2 % n; int b = t2 / n;
    int it0 = itb * 4;

    float acc[9][4];
    #pragma unroll
    for (int o = 0; o < 9; ++o)
        #pragma unroll
        for (int tt = 0; tt < 4; ++tt) acc[o][tt] = scb[o];

    for (int dx = -1; dx <= 1; ++dx) {
        int jx = ix + dx;
        bool okx = (unsigned)jx < (unsigned)n;
        int cjx = okx ? jx : ix;
        for (int dy = -1; dy <= 1; ++dy) {
            int jy = iy + dy;
            bool okxy = okx && ((unsigned)jy < (unsigned)n);
            int cjy = ((unsigned)jy < (unsigned)n) ? jy : iy;
            const float* p = in + (((size_t)(b*n + cjx) * n + cjy) * 64 + it0) * 9 - 9;
            float win[6][9];
            #pragma unroll
            for (int k = 0; k < 6; ++k) {
                int jt = it0 - 1 + k;
                bool ok = okxy && (jt >= 0) && (jt < 64);
                #pragma unroll
                for (int ic = 0; ic < 9; ++ic)
                    win[k][ic] = ok ? p[k*9 + ic] : 0.f;
            }
            #pragma unroll
            for (int dt = 0; dt < 3; ++dt) {
                int wo = ((dx+1)*3 + (dy+1))*3 + dt;
                #pragma unroll
                for (int o = 0; o < 9; ++o)
                    #pragma unroll
                    for (int ic = 0; ic < 9; ++ic) {
                        float wv = scw[(o*9+ic)*27 + wo];
                        #pragma unroll
                        for (int tt = 0; tt < 4; ++tt)
                            acc[o][tt] += win[tt+dt][ic] * wv;
                    }
            }
        }
    }
    #pragma unroll
    for (int tt = 0; tt < 4; ++tt) {
        float r[9];
        #pragma unroll
        for (int o = 0; o < 9; ++o) r[o] = fmaxf(acc[o][tt], 0.f);
        size_t ob = ((size_t)tmp * 64 + it0 + tt) * 9;
        #pragma unroll
        for (int o2 = 0; o2 < 9; ++o2) {
            float v = slb[o2];
            #pragma unroll
            for (int o = 0; o < 9; ++o) v += r[o] * slw[o2*9+o];
            if (which == 0) out[ob+o2] += v; else out[ob+o2] = v;
        }
    }
}

// ---------------- forward z DFT: [site,64,9] -> [site, kz(5), ic(9)] complex ----------------
__global__ void fwdz_kernel(const float* __restrict__ in, float2* __restrict__ Fz, int total)
{
    int idx = blockIdx.x * blockDim.x + threadIdx.x;
    if (idx >= total) return;
    int ic = idx % 9; int tmp = idx / 9;
    int kz = tmp % 5; int site = tmp / 5;
    const float* p = in + (size_t)site * 64 * 9 + ic;
    float re = 0.f, im = 0.f;
    for (int it = 0; it < 64; ++it) {
        int m = (kz * it) & 63;
        float sv, cv; __sincosf((TWO_PI / 64.0f) * m, &sv, &cv);
        float v = p[(size_t)it * 9];
        re += v * cv; im -= v * sv;
    }
    Fz[idx] = make_float2(re, im);
}

// ---------------- forward y DFT (kept modes only) ----------------
__global__ void fwdy_kernel(const float2* __restrict__ Fz, float2* __restrict__ Fzy,
                            int n, int L, int l1, int total)
{
    int idx = blockIdx.x * blockDim.x + threadIdx.x;
    if (idx >= total) return;
    int c45 = idx % 45; int tmp = idx / 45;
    int kyI = tmp % L; tmp /= L;
    int ix = tmp % n; int b = tmp / n;
    int ky = (kyI < l1) ? kyI : (n - L + kyI);
    const float2* p = Fz + ((size_t)(b * n + ix) * n) * 45 + c45;
    float re = 0.f, im = 0.f;
    for (int iy = 0; iy < n; ++iy) {
        int m = (ky * iy) & (n - 1);
        float sv, cv; __sincosf((TWO_PI / n) * m, &sv, &cv);
        float2 a = p[(size_t)iy * 45];
        re += a.x * cv + a.y * sv;   // a * e^{-i theta}
        im += a.y * cv - a.x * sv;
    }
    Fzy[idx] = make_float2(re, im);
}

// ------- fused forward-x DFT + 9x9 complex mode mix (corner priority w4>w3>w2>w1) -------
// one block per (b, kyI); stages Fzy row and F in LDS
__global__ void fwdxmix_kernel(const float2* __restrict__ Fzy, float2* __restrict__ M,
                               const float* __restrict__ w1, const float* __restrict__ w2,
                               const float* __restrict__ w3, const float* __restrict__ w4,
                               int n, int L, int l1)
{
    __shared__ float2 sFzy[32*45];
    __shared__ float2 sF[10*45];
    int kyI = blockIdx.x % L;
    int b   = blockIdx.x / L;
    int ky = (kyI < l1) ? kyI : (n - L + kyI);
    // phase 0: stage Fzy[b, :, kyI, :]
    int nload = n * 45;
    for (int i = threadIdx.x; i < nload; i += blockDim.x) {
        int ix = i / 45, c = i % 45;
        sFzy[i] = Fzy[((size_t)(b * n + ix) * L + kyI) * 45 + c];
    }
    __syncthreads();
    // phase 1: forward-x DFT for kept kx modes
    int nf = L * 45;
    for (int i = threadIdx.x; i < nf; i += blockDim.x) {
        int kxI = i / 45, c = i % 45;
        int kx = (kxI < l1) ? kxI : (n - L + kxI);
        float re = 0.f, im = 0.f;
        for (int ix = 0; ix < n; ++ix) {
            int m = (kx * ix) & (n - 1);
            float sv, cv; __sincosf((TWO_PI / n) * m, &sv, &cv);
            float2 a = sFzy[ix * 45 + c];
            re += a.x * cv + a.y * sv;
            im += a.y * cv - a.x * sv;
        }
        sF[i] = make_float2(re, im);
    }
    __syncthreads();
    // phase 2: per-mode 9x9 complex channel mix
    bool ly = ky < l1, hy = ky >= n - l1;
    for (int i = threadIdx.x; i < nf; i += blockDim.x) {
        int kxI = i / 45, c = i % 45;
        int kz = c / 9, oc = c % 9;
        int kx = (kxI < l1) ? kxI : (n - L + kxI);
        bool lx = kx < l1, hx = kx >= n - l1;
        const float* w; int wx, wy;
        if (hx && hy)      { w = w4; wx = kx - (n - l1); wy = ky - (n - l1); }
        else if (lx && hy) { w = w3; wx = kx;            wy = ky - (n - l1); }
        else if (hx && ly) { w = w2; wx = kx - (n - l1); wy = ky; }
        else               { w = w1; wx = kx;            wy = ky; }
        const float* wb = w + (((size_t)oc * 5 + wx) * 5 + wy) * 10 + kz * 2;
        const float2* pf = &sF[kxI * 45 + kz * 9];
        float re = 0.f, im = 0.f;
        #pragma unroll
        for (int ic = 0; ic < 9; ++ic) {
            float2 a = pf[ic];
            float wr = wb[(size_t)ic * 2250];
            float wi = wb[(size_t)ic * 2250 + 1];
            re += a.x * wr - a.y * wi;
            im += a.x * wi + a.y * wr;
        }
        M[(((size_t)(b * L + kxI) * L + kyI) * 5 + kz) * 9 + oc] = make_float2(re, im);
    }
}

// ---------------- inverse x (zero-padded modes -> full axis) ----------------
__global__ void invx_kernel(const float2* __restrict__ M, float2* __restrict__ G1,
                            int n, int L, int l1, int total)
{
    int idx = blockIdx.x * blockDim.x + threadIdx.x;
    if (idx >= total) return;
    int c45 = idx % 45; int tmp = idx / 45;
    int kyI = tmp % L; tmp /= L;
    int ix = tmp % n; int b = tmp / n;
    const float2* p = M + ((size_t)b * L * L) * 45 + (size_t)kyI * 45 + c45;
    float re = 0.f, im = 0.f;
    for (int kxI = 0; kxI < L; ++kxI) {
        int kx = (kxI < l1) ? kxI : (n - L + kxI);
        int m = (kx * ix) & (n - 1);
        float sv, cv; __sincosf((TWO_PI / n) * m, &sv, &cv);
        float2 a = p[(size_t)kxI * L * 45];
        re += a.x * cv - a.y * sv;   // a * e^{+i theta}
        im += a.x * sv + a.y * cv;
    }
    G1[idx] = make_float2(re, im);
}

// ------- fused inverse-y + inverse-z(c2r) + ReLU + Linear: one block per (b,ix,iy-tile) -------
__global__ void invyz_kernel(const float2* __restrict__ G1, float* __restrict__ out,
                             const float* __restrict__ lw, const float* __restrict__ lb,
                             int n, int L, int l1, int TY, int NT, float inv_norm)
{
    __shared__ float2 sG1[10*45];
    __shared__ float2 sG2[4*45];
    __shared__ float slw[81], slb[9];
    int iyt = blockIdx.x % NT;
    int ix  = (blockIdx.x / NT) % n;
    int b   = blockIdx.x / (NT * n);
    int iy0 = iyt * TY;
    if (threadIdx.x < 81) slw[threadIdx.x] = lw[threadIdx.x];
    if (threadIdx.x < 9)  slb[threadIdx.x] = lb[threadIdx.x];
    // phase 0: stage G1[b, ix, :, :]
    int nload = L * 45;
    for (int i = threadIdx.x; i < nload; i += blockDim.x)
        sG1[i] = G1[((size_t)(b * n + ix) * L) * 45 + i];
    __syncthreads();
    // phase 1: inverse-y for TY rows
    int nf = TY * 45;
    for (int i = threadIdx.x; i < nf; i += blockDim.x) {
        int il = i / 45, c = i % 45;
        int iy = iy0 + il;
        float re = 0.f, im = 0.f;
        for (int kyI = 0; kyI < L; ++kyI) {
            int ky = (kyI < l1) ? kyI : (n - L + kyI);
            int m = (ky * iy) & (n - 1);
            float sv, cv; __sincosf((TWO_PI / n) * m, &sv, &cv);
            float2 a = sG1[kyI * 45 + c];
            re += a.x * cv - a.y * sv;
            im += a.x * sv + a.y * cv;
        }
        sG2[i] = make_float2(re, im);
    }
    __syncthreads();
    // phase 2: inverse-z (c2r drops Im) + ReLU + Linear; one thread per (il, it)
    int t = threadIdx.x;
    if (t < TY * 64) {
        int il = t >> 6, it = t & 63;
        float cvz[5], svz[5];
        #pragma unroll
        for (int kz = 0; kz < 5; ++kz) {
            int m = (kz * it) & 63;
            __sincosf((TWO_PI / 64.0f) * m, &svz[kz], &cvz[kz]);
        }
        const float2* pg = &sG2[il * 45];
        float y[9];
        #pragma unroll
        for (int oc = 0; oc < 9; ++oc) {
            float v = 0.f;
            #pragma unroll
            for (int kz = 0; kz < 5; ++kz) {
                float2 a = pg[kz * 9 + oc];
                float term = a.x * cvz[kz] - a.y * svz[kz];
                v += (kz == 0 ? 1.0f : 2.0f) * term;
            }
            y[oc] = fmaxf(v * inv_norm, 0.f);
        }
        size_t site = ((size_t)(b * n + ix) * n + iy0 + il) * 64 + it;
        size_t ob = site * 9;
        #pragma unroll
        for (int o2 = 0; o2 < 9; ++o2) {
            float v = slb[o2];
            #pragma unroll
            for (int oc = 0; oc < 9; ++oc) v += y[oc] * slw[o2*9+oc];
            out[ob + o2] = v;
        }
    }
}

// ------- reconstruct: (x(+T0)+Us | Ud) -> even/odd interleave to [b,2n,2n,64,9] -------
__global__ void recon_kernel(const float* __restrict__ x, const float* __restrict__ Us,
                             const float* __restrict__ Ud, float* __restrict__ out,
                             const float* __restrict__ ree, const float* __restrict__ reo,
                             const float* __restrict__ roe, const float* __restrict__ roo,
                             const float* __restrict__ t0w, const float* __restrict__ t0b,
                             int n, int total, int apply_t0)
{
    __shared__ float s_m[4][162];
    __shared__ float st0[81], st0b[9];
    for (int i = threadIdx.x; i < 162; i += blockDim.x) {
        s_m[0][i] = ree[i]; s_m[1][i] = reo[i]; s_m[2][i] = roe[i]; s_m[3][i] = roo[i];
    }
    if (threadIdx.x < 81) st0[threadIdx.x] = t0w[threadIdx.x];
    if (threadIdx.x < 9)  st0b[threadIdx.x] = t0b[threadIdx.x];
    __syncthreads();
    int idx = blockIdx.x * blockDim.x + threadIdx.x;
    if (idx >= total) return;
    int it = idx & 63; int tmp = idx >> 6;
    int iy = tmp % n; tmp /= n;
    int ix = tmp % n; int b = tmp / n;
    float v[18];
    size_t ib = (size_t)idx * 9;
    if (apply_t0) {
        float xr[9];
        #pragma unroll
        for (int k = 0; k < 9; ++k) xr[k] = x[ib+k];
        #pragma unroll
        for (int o = 0; o < 9; ++o) {
            float r = st0b[o];
            #pragma unroll
            for (int i = 0; i < 9; ++i) r += xr[i] * st0[o*9+i];
            v[o] = r + Us[ib+o];
        }
    } else {
        #pragma unroll
        for (int k = 0; k < 9; ++k) v[k] = x[ib+k] + Us[ib+k];
    }
    #pragma unroll
    for (int k = 0; k < 9; ++k) v[9+k] = Ud[ib+k];
    int n2 = 2 * n;
    #pragma unroll
    for (int q = 0; q < 4; ++q) {
        int rx = q >> 1, ry = q & 1;
        size_t ob = ((((size_t)(b * n2 + 2*ix + rx) * n2) + 2*iy + ry) * 64 + it) * 9;
        const float* mm = s_m[q];
        #pragma unroll
        for (int oc = 0; oc < 9; ++oc) {
            float r = 0.f;
            #pragma unroll
            for (int k = 0; k < 18; ++k) r += v[k] * mm[k*9+oc];
            out[ob + oc] = r;
        }
    }
}

extern "C" void kernel_launch(void* const* d_in, const int* in_sizes, int n_in,
                              void* d_out, int out_size, void* d_ws, size_t ws_size,
                              hipStream_t stream)
{
    const float* x0    = (const float*)d_in[0];
    const float* ec_s  = (const float*)d_in[1];
    const float* ec_d  = (const float*)d_in[2];
    const float* rc_ee = (const float*)d_in[3];
    const float* rc_eo = (const float*)d_in[4];
    const float* rc_oe = (const float*)d_in[5];
    const float* rc_oo = (const float*)d_in[6];
    const float* w1    = (const float*)d_in[7];
    const float* w2    = (const float*)d_in[8];
    const float* w3    = (const float*)d_in[9];
    const float* w4    = (const float*)d_in[10];
    const float* A_Lo_w = (const float*)d_in[11];
    const float* A_Lo_b = (const float*)d_in[12];
    const float* B_cw  = (const float*)d_in[13];
    const float* B_cb  = (const float*)d_in[14];
    const float* B_lw  = (const float*)d_in[15];
    const float* B_lb  = (const float*)d_in[16];
    const float* C_cw  = (const float*)d_in[17];
    const float* C_cb  = (const float*)d_in[18];
    const float* C_lw  = (const float*)d_in[19];
    const float* C_lb  = (const float*)d_in[20];
    const float* T0_w  = (const float*)d_in[21];
    const float* T0_b  = (const float*)d_in[22];

    float* ws = (float*)d_ws;
    size_t off = 0;
    auto alloc = [&](size_t nf) { float* p = ws + off; off += (nf + 3) & ~(size_t)3; return p; };

    int ns_[6] = {32, 16, 8, 4, 2, 1};
    size_t Ssz[6];
    float* sb[6]; float* UdB[6]; float* UsB[6];
    for (int i = 0; i < 6; ++i) Ssz[i] = (size_t)8 * ns_[i] * ns_[i] * 64 * 9;
    for (int i = 0; i < 6; ++i) sb[i]  = alloc(Ssz[i]);
    for (int i = 0; i < 6; ++i) UdB[i] = alloc(Ssz[i]);
    for (int i = 0; i < 6; ++i) UsB[i] = alloc(Ssz[i]);
    float* dbuf = alloc(Ssz[0]);
    float2* tA = (float2*)alloc(2 * 368640);  // [8,n,n,5,9] complex, max at n=32
    float2* tB = (float2*)alloc(2 * 115200);  // [8,n,L,5,9]
    float2* tD = (float2*)alloc(2 * 36000);   // [8,L,L,5,9]

    const int BLK = 256;
    for (int lev = 0; lev < 6; ++lev) {
        int n = ns_[lev];
        const float* xin = (lev == 0) ? x0 : sb[lev-1];
        int total = 8 * n * n * 64;
        int nblk = (total + BLK - 1) / BLK;
        wavelet_kernel<<<nblk, BLK, 0, stream>>>(xin, dbuf, sb[lev], ec_d, ec_s, n, total);

        int l1 = (n/2 + 1 < 5) ? (n/2 + 1) : 5;
        int L  = (2*l1 < n) ? 2*l1 : n;
        int t1 = 8 * n * n * 45;
        int t2 = 8 * n * L * 45;
        fwdz_kernel<<<(t1+BLK-1)/BLK, BLK, 0, stream>>>(dbuf, tA, t1);
        fwdy_kernel<<<(t2+BLK-1)/BLK, BLK, 0, stream>>>(tA, tB, n, L, l1, t2);
        fwdxmix_kernel<<<8*L, BLK, 0, stream>>>(tB, tD, w1, w2, w3, w4, n, L, l1);
        invx_kernel<<<(t2+BLK-1)/BLK, BLK, 0, stream>>>(tD, tB, n, L, l1, t2);
        int TY = (n < 4) ? n : 4;
        int NT = n / TY;
        invyz_kernel<<<8*n*NT, BLK, 0, stream>>>(tB, UdB[lev], A_Lo_w, A_Lo_b,
                                                 n, L, l1, TY, NT,
                                                 1.0f / ((float)n * (float)n * 64.0f));
        int total4 = total / 4;
        dim3 cgrid((total4 + BLK - 1) / BLK, 2);
        conv2_kernel<<<cgrid, BLK, 0, stream>>>(sb[lev], UdB[lev], dbuf, UsB[lev],
                                                B_cw, B_cb, B_lw, B_lb,
                                                C_cw, C_cb, C_lw, C_lb, n, total4);
    }

    // reconstruct (lev 5 applies T0 to its x-input inline)
    float* cur = nullptr;
    for (int lev = 5; lev >= 0; --lev) {
        int n = ns_[lev];
        int total = 8 * n * n * 64;
        const float* xin = (lev == 5) ? sb[5] : cur;
        float* outp = (lev == 0) ? (float*)d_out : ((cur == dbuf) ? sb[0] : dbuf);
        recon_kernel<<<(total+BLK-1)/BLK, BLK, 0, stream>>>(xin, UsB[lev], UdB[lev], outp,
                                                            rc_ee, rc_eo, rc_oe, rc_oo,
                                                            T0_w, T0_b, n, total, (lev == 5) ? 1 : 0);
        cur = outp;
    }
}